// Round 2
// baseline (368.571 us; speedup 1.0000x reference)
//
#include <hip/hip_runtime.h>

// EmbeddingBag(mean): V=1e6, D=64, B=16384, L=50.
//
// R2: two-launch scheme = {warm-L3 streaming pass over weight} + {gather}.
// Evidence: R1 (removing all cross-lane ops) was a perfect null vs R0 -> the
// gather is memory-system-bound, not instruction/latency-bound. Decomposition:
// dur 324.8 = ~155us harness poison-fill (1.024GB @6.6TB/s, visible in
// rocprof) + restore ops + gather kernel at ~90-150us for ~150-210MB of
// random 256B rows = ~1.0-1.7 TB/s effective -- the DRAM row-activation wall
// for scattered 256B requests (sequential fills sustain 6.6TB/s on the same
// chip in the same graph).
// Fix attempt: the 256MB table fits in the 256MiB memory-side Infinity Cache.
// A sequential pass (streaming-efficient, ~45us) populates L3; the random
// gathers then hit L3 instead of opening a DRAM page each. Poison fill
// re-flushes L3 every iteration, so the warm pass runs every iteration and
// its cost is in the budget.
// Prediction: total 325 -> ~250-270 (gather leg 90-150 -> 25-40). If total
// RISES by ~the warm cost, L3 does not accelerate random 256B gathers and the
// DRAM wall was already the floor -> revert next round.

constexpr int kBagsPerBlock = 16;  // 256 threads = 4 waves x 4 bags/wave
constexpr int kMaxFast = 64;       // fast path when bag count <= 64 (L=50 here)

// Sequential coalesced read of the whole table: populates memory-side L3 at
// streaming efficiency. Sum is kept live via a never-taken guarded store.
__global__ __launch_bounds__(256) void warm_l3_kernel(
    const float4* __restrict__ weight4, unsigned long long n4,
    float* __restrict__ sink)
{
    float acc = 0.f;
    const unsigned long long stride = (unsigned long long)gridDim.x * blockDim.x;
    for (unsigned long long i = (unsigned long long)blockIdx.x * blockDim.x + threadIdx.x;
         i < n4; i += stride) {
        const float4 v = weight4[i];
        acc += v.x + v.y + v.z + v.w;
    }
    if (acc == 1234567.89f && sink) sink[0] = acc;  // keep loads live; never true
}

__global__ __launch_bounds__(256) void FreqAwareEmbedding_kernel(
    const int* __restrict__ indices,    // [T]
    const int* __restrict__ offsets,    // [B]
    const float4* __restrict__ weight4, // [V*16] (V x 64 fp32 as float4)
    float4* __restrict__ out4,          // [B*16]
    int B, int T)
{
    // +1 pad: group bases differ by 65 words -> the 4 concurrent broadcast
    // reads of a wave hit 4 distinct banks.
    __shared__ int sidx[kBagsPerBlock][kMaxFast + 1];

    const int tid = threadIdx.x;
    const int grp = tid >> 4;       // 0..15: bag slot within block
    const int col = tid & 15;       // float4 column within the 64-float row
    const int bag = blockIdx.x * kBagsPerBlock + grp;

    int start = 0, count = 0;
    if (bag < B) {
        start = offsets[bag];
        const int end = (bag + 1 < B) ? offsets[bag + 1] : T;
        count = end - start;
    }

    const bool fast = (count <= kMaxFast);  // uniform within the 16-lane group
    if (fast) {
        for (int j = col; j < count; j += 16)
            sidx[grp][j] = indices[start + j];
    }
    __syncthreads();

    float4 acc = make_float4(0.f, 0.f, 0.f, 0.f);

    if (fast) {
        const int* sp = sidx[grp];
        int j = 0;
        // 10-deep pipeline: 10 broadcast LDS reads, then 10 independent 256B
        // row-gathers in flight before the accumulate chain drains them.
        for (; j + 10 <= count; j += 10) {
            int id[10];
            #pragma unroll
            for (int u = 0; u < 10; ++u) id[u] = sp[j + u];
            #pragma unroll
            for (int u = 0; u < 10; ++u) {
                const float4 v = weight4[(size_t)id[u] * 16 + col];
                acc.x += v.x; acc.y += v.y; acc.z += v.z; acc.w += v.w;
            }
        }
        for (; j < count; ++j) {
            const float4 v = weight4[(size_t)sp[j] * 16 + col];
            acc.x += v.x; acc.y += v.y; acc.z += v.z; acc.w += v.w;
        }
    } else if (count > 0) {
        for (int j = 0; j < count; ++j) {
            const float4 v = weight4[(size_t)indices[start + j] * 16 + col];
            acc.x += v.x; acc.y += v.y; acc.z += v.z; acc.w += v.w;
        }
    }

    if (bag < B) {
        const float inv = 1.0f / (float)((count > 0) ? count : 1);
        acc.x *= inv; acc.y *= inv; acc.z *= inv; acc.w *= inv;
        out4[(size_t)bag * 16 + col] = acc;  // 256B/bag, coalesced
    }
}

extern "C" void kernel_launch(void* const* d_in, const int* in_sizes, int n_in,
                              void* d_out, int out_size, void* d_ws, size_t ws_size,
                              hipStream_t stream) {
    const int*   indices = (const int*)d_in[0];
    const int*   offsets = (const int*)d_in[1];
    const float* weight  = (const float*)d_in[2];

    const int T = in_sizes[0];
    const int B = in_sizes[1];
    // in_sizes are element counts ([0]=T matches indices length), so [2] is
    // the number of floats in weight (V*D).
    const unsigned long long n4 = (unsigned long long)in_sizes[2] >> 2;

    float* sink = (ws_size >= sizeof(float)) ? (float*)d_ws : (float*)d_out;

    // Phase 1: stream the table sequentially to populate Infinity Cache.
    warm_l3_kernel<<<2048, 256, 0, stream>>>(
        (const float4*)weight, n4, sink);

    // Phase 2: random row gathers now hit L3 instead of DRAM pages.
    const int grid = (B + kBagsPerBlock - 1) / kBagsPerBlock;  // 1024 blocks
    FreqAwareEmbedding_kernel<<<grid, 256, 0, stream>>>(
        indices, offsets, (const float4*)weight, (float4*)d_out, B, T);
}